// Round 1
// baseline (74.037 us; speedup 1.0000x reference)
//
#include <hip/hip_runtime.h>
#include <math.h>

#define NQ 10
#define NS 1024            // 2^NQ amplitudes
#define NDEPTH 4

// One block per batch element. 512 threads; each thread owns one
// amplitude-pair per gate (pairs are disjoint -> only inter-gate barriers).
// Qubit q corresponds to bit k = NQ-1-q of the flat state index
// (reference reshape (B, 2^q, 2, 2^(n-q-1)) puts qubit 0 at the MSB).
__global__ __launch_bounds__(512) void vql_kernel(
    const float* __restrict__ x,     // (B, NQ)
    const float* __restrict__ w,     // (NDEPTH, NQ)
    float* __restrict__ out)         // (B, NQ)
{
    __shared__ float sre[NS];
    __shared__ float sim[NS];
    __shared__ float wred[8 * NQ];

    const int b = blockIdx.x;
    const int t = threadIdx.x;

    // init |0...0>
    sre[t] = 0.f;       sim[t] = 0.f;
    sre[t + 512] = 0.f; sim[t + 512] = 0.f;
    if (t == 0) sre[0] = 1.f;
    __syncthreads();

    // ---- RY encoding layer (per-batch angles) ----
    #pragma unroll
    for (int q = 0; q < NQ; ++q) {
        const float th = 0.5f * x[b * NQ + q];
        float s, c;
        __sincosf(th, &s, &c);
        const int k = NQ - 1 - q;
        const int p = t;
        const int i0 = ((p >> k) << (k + 1)) | (p & ((1 << k) - 1));
        const int i1 = i0 | (1 << k);
        const float r0 = sre[i0], m0 = sim[i0];
        const float r1 = sre[i1], m1 = sim[i1];
        // RY: new0 = c*a0 - s*a1 ; new1 = s*a0 + c*a1   (real coeffs)
        sre[i0] = c * r0 - s * r1;
        sim[i0] = c * m0 - s * m1;
        sre[i1] = s * r0 + c * r1;
        sim[i1] = s * m0 + c * m1;
        __syncthreads();
    }

    // ---- variational layers ----
    for (int l = 0; l < NDEPTH; ++l) {
        // RX rotations (shared weights)
        #pragma unroll
        for (int q = 0; q < NQ; ++q) {
            const float th = 0.5f * w[l * NQ + q];
            float s, c;
            __sincosf(th, &s, &c);
            const int k = NQ - 1 - q;
            const int p = t;
            const int i0 = ((p >> k) << (k + 1)) | (p & ((1 << k) - 1));
            const int i1 = i0 | (1 << k);
            const float r0 = sre[i0], m0 = sim[i0];
            const float r1 = sre[i1], m1 = sim[i1];
            // RX: new0 = c*a0 - i*s*a1 ; new1 = -i*s*a0 + c*a1
            sre[i0] = c * r0 + s * m1;
            sim[i0] = c * m0 - s * r1;
            sre[i1] = s * m0 + c * r1;
            sim[i1] = -s * r0 + c * m1;
            __syncthreads();
        }
        // CNOT ring: ctrl q -> tgt (q+1)%NQ
        #pragma unroll
        for (int q = 0; q < NQ; ++q) {
            const int cq = q;
            const int tq = (q + 1) % NQ;
            const int kc = NQ - 1 - cq;
            const int kt = NQ - 1 - tq;
            if (t < 256) {
                const int klo = (kc < kt) ? kc : kt;
                const int khi = (kc < kt) ? kt : kc;
                int i = t;  // 8 free bits
                i = ((i >> klo) << (klo + 1)) | (i & ((1 << klo) - 1));
                i = ((i >> khi) << (khi + 1)) | (i & ((1 << khi) - 1));
                const int ia = i | (1 << kc);        // ctrl=1, tgt=0
                const int ib = ia | (1 << kt);       // ctrl=1, tgt=1
                const float r = sre[ia], m = sim[ia];
                sre[ia] = sre[ib]; sim[ia] = sim[ib];
                sre[ib] = r;       sim[ib] = m;
            }
            __syncthreads();
        }
    }

    // ---- readout: z[q] = sum_i probs[i] * (1 - 2*bit_{NQ-1-q}(i)) ----
    const int iA = t;
    const int iB = t + 512;
    const float prA = sre[iA] * sre[iA] + sim[iA] * sim[iA];
    const float prB = sre[iB] * sre[iB] + sim[iB] * sim[iB];

    float zq[NQ];
    #pragma unroll
    for (int q = 0; q < NQ; ++q) {
        const int k = NQ - 1 - q;
        const float sA = ((iA >> k) & 1) ? -prA : prA;
        const float sB = ((iB >> k) & 1) ? -prB : prB;
        zq[q] = sA + sB;
    }

    const int lane = t & 63;
    const int wv = t >> 6;
    #pragma unroll
    for (int q = 0; q < NQ; ++q) {
        float v = zq[q];
        #pragma unroll
        for (int off = 32; off > 0; off >>= 1)
            v += __shfl_down(v, off, 64);
        if (lane == 0) wred[wv * NQ + q] = v;
    }
    __syncthreads();
    if (t < NQ) {
        float acc = 0.f;
        #pragma unroll
        for (int w8 = 0; w8 < 8; ++w8) acc += wred[w8 * NQ + t];
        out[b * NQ + t] = acc;
    }
}

extern "C" void kernel_launch(void* const* d_in, const int* in_sizes, int n_in,
                              void* d_out, int out_size, void* d_ws, size_t ws_size,
                              hipStream_t stream) {
    const float* x = (const float*)d_in[0];        // (BATCH, NQ) fp32
    const float* w = (const float*)d_in[1];        // (NDEPTH, NQ) fp32
    float* out = (float*)d_out;                    // (BATCH, NQ) fp32
    const int B = in_sizes[0] / NQ;
    vql_kernel<<<B, 512, 0, stream>>>(x, w, out);
}

// Round 2
// 32.904 us; speedup vs baseline: 2.2501x; 2.2501x over previous
//
#include <hip/hip_runtime.h>
#include <math.h>

#define NQ 10
#define NDEPTH 4
#define NR 16              // amplitudes per lane (2^4)

// One WAVE per batch element: 64 lanes x 16 complex amps = 1024 amplitudes.
// Flat index i = lane*16 + r. Qubit q <-> bit k = 9-q of i:
//   q 0..5  -> lane bit (5-q), shfl mask M = 32 >> q
//   q 6..9  -> register bit (9-q)
// No LDS, no barriers; cross-lane traffic via ds_swizzle/bpermute only.

template<int M, bool IS_RX>
__device__ __forceinline__ void rot_lanebit(float (&re)[NR], float (&im)[NR],
                                            float c, float s, int lane) {
    const float sgn = (lane & M) ? s : -s;   // RY only
    #pragma unroll
    for (int r = 0; r < NR; ++r) {
        const float pre = __shfl_xor(re[r], M, 64);
        const float pim = __shfl_xor(im[r], M, 64);
        if (IS_RX) {
            // same expression for both halves of the pair
            re[r] = c * re[r] + s * pim;
            im[r] = c * im[r] - s * pre;
        } else {
            re[r] = c * re[r] + sgn * pre;
            im[r] = c * im[r] + sgn * pim;
        }
    }
}

template<int J, bool IS_RX>
__device__ __forceinline__ void rot_regbit(float (&re)[NR], float (&im)[NR],
                                           float c, float s) {
    #pragma unroll
    for (int r0 = 0; r0 < NR; ++r0) {
        if (r0 & (1 << J)) continue;
        const int r1 = r0 | (1 << J);
        const float R0 = re[r0], M0 = im[r0];
        const float R1 = re[r1], M1 = im[r1];
        if (IS_RX) {
            re[r0] = c * R0 + s * M1;
            im[r0] = c * M0 - s * R1;
            re[r1] = c * R1 + s * M0;
            im[r1] = c * M1 - s * R0;
        } else {
            re[r0] = c * R0 - s * R1;
            im[r0] = c * M0 - s * M1;
            re[r1] = s * R0 + c * R1;
            im[r1] = s * M0 + c * M1;
        }
    }
}

__global__ __launch_bounds__(256) void vql_kernel(
    const float* __restrict__ x,     // (B, NQ)
    const float* __restrict__ w,     // (NDEPTH, NQ)
    float* __restrict__ out,         // (B, NQ)
    int B)
{
    const int lane = threadIdx.x & 63;
    const int b = blockIdx.x * 4 + (threadIdx.x >> 6);
    if (b >= B) return;

    float re[NR], im[NR];
    #pragma unroll
    for (int r = 0; r < NR; ++r) { re[r] = 0.f; im[r] = 0.f; }
    if (lane == 0) re[0] = 1.f;

    // ---- RY encoding layer ----
    {
        float c, s;
        #define RY_LANE(q) { __sincosf(0.5f * x[b*NQ + (q)], &s, &c); \
                             rot_lanebit<(32 >> (q)), false>(re, im, c, s, lane); }
        RY_LANE(0) RY_LANE(1) RY_LANE(2) RY_LANE(3) RY_LANE(4) RY_LANE(5)
        #undef RY_LANE
        __sincosf(0.5f * x[b*NQ + 6], &s, &c); rot_regbit<3, false>(re, im, c, s);
        __sincosf(0.5f * x[b*NQ + 7], &s, &c); rot_regbit<2, false>(re, im, c, s);
        __sincosf(0.5f * x[b*NQ + 8], &s, &c); rot_regbit<1, false>(re, im, c, s);
        __sincosf(0.5f * x[b*NQ + 9], &s, &c); rot_regbit<0, false>(re, im, c, s);
    }

    // ---- variational layers ----
    #pragma unroll
    for (int l = 0; l < NDEPTH; ++l) {
        float c, s;
        // RX on all 10 qubits
        #define RX_LANE(q) { __sincosf(0.5f * w[l*NQ + (q)], &s, &c); \
                             rot_lanebit<(32 >> (q)), true>(re, im, c, s, lane); }
        RX_LANE(0) RX_LANE(1) RX_LANE(2) RX_LANE(3) RX_LANE(4) RX_LANE(5)
        #undef RX_LANE
        __sincosf(0.5f * w[l*NQ + 6], &s, &c); rot_regbit<3, true>(re, im, c, s);
        __sincosf(0.5f * w[l*NQ + 7], &s, &c); rot_regbit<2, true>(re, im, c, s);
        __sincosf(0.5f * w[l*NQ + 8], &s, &c); rot_regbit<1, true>(re, im, c, s);
        __sincosf(0.5f * w[l*NQ + 9], &s, &c); rot_regbit<0, true>(re, im, c, s);

        // CNOTs (0->1),(1->2),(2->3),(3->4),(4->5): lane-lane, composed into
        // ONE bpermute pass. src = gA(gB(gC(gD(gE(lane))))), innermost = last gate.
        {
            int j = lane;
            j ^= ((j >> 1) & 1);            // C(4->5): ctrl bit1 -> tgt bit0
            j ^= ((j >> 2) & 1) << 1;       // C(3->4)
            j ^= ((j >> 3) & 1) << 2;       // C(2->3)
            j ^= ((j >> 4) & 1) << 3;       // C(1->2)
            j ^= ((j >> 5) & 1) << 4;       // C(0->1)
            #pragma unroll
            for (int r = 0; r < NR; ++r) {
                re[r] = __shfl(re[r], j, 64);
                im[r] = __shfl(im[r], j, 64);
            }
        }
        // C(5->6): ctrl lane bit0, tgt reg bit3 -> conditional reg swap
        {
            const bool ctl = (lane & 1) != 0;
            #pragma unroll
            for (int r = 0; r < 8; ++r) {
                const float a0 = re[r], a1 = re[r + 8];
                re[r] = ctl ? a1 : a0;  re[r + 8] = ctl ? a0 : a1;
                const float b0 = im[r], b1 = im[r + 8];
                im[r] = ctl ? b1 : b0;  im[r + 8] = ctl ? b0 : b1;
            }
        }
        // C(6->7): regs with bit3=1 swap bit2 -> (8,12),(9,13),(10,14),(11,15)
        #pragma unroll
        for (int r = 8; r < 12; ++r) {
            float t = re[r]; re[r] = re[r + 4]; re[r + 4] = t;
            t = im[r]; im[r] = im[r + 4]; im[r + 4] = t;
        }
        // C(7->8): regs with bit2=1 swap bit1 -> (4,6),(5,7),(12,14),(13,15)
        {
            const int rs[4] = {4, 5, 12, 13};
            #pragma unroll
            for (int k = 0; k < 4; ++k) {
                const int r = rs[k];
                float t = re[r]; re[r] = re[r + 2]; re[r + 2] = t;
                t = im[r]; im[r] = im[r + 2]; im[r + 2] = t;
            }
        }
        // C(8->9): regs with bit1=1 swap bit0 -> (2,3),(6,7),(10,11),(14,15)
        {
            const int rs[4] = {2, 6, 10, 14};
            #pragma unroll
            for (int k = 0; k < 4; ++k) {
                const int r = rs[k];
                float t = re[r]; re[r] = re[r + 1]; re[r + 1] = t;
                t = im[r]; im[r] = im[r + 1]; im[r + 1] = t;
            }
        }
        // C(9->0): ctrl reg bit0, tgt lane mask 32 -> shuffle odd regs
        #pragma unroll
        for (int r = 1; r < NR; r += 2) {
            re[r] = __shfl_xor(re[r], 32, 64);
            im[r] = __shfl_xor(im[r], 32, 64);
        }
    }

    // ---- readout ----
    float p[NR];
    #pragma unroll
    for (int r = 0; r < NR; ++r) p[r] = re[r] * re[r] + im[r] * im[r];

    float ptot = 0.f, z6 = 0.f, z7 = 0.f, z8 = 0.f, z9 = 0.f;
    #pragma unroll
    for (int r = 0; r < NR; ++r) {
        ptot += p[r];
        z6 += (r & 8) ? -p[r] : p[r];
        z7 += (r & 4) ? -p[r] : p[r];
        z8 += (r & 2) ? -p[r] : p[r];
        z9 += (r & 1) ? -p[r] : p[r];
    }
    float z[NQ];
    z[0] = (lane & 32) ? -ptot : ptot;
    z[1] = (lane & 16) ? -ptot : ptot;
    z[2] = (lane &  8) ? -ptot : ptot;
    z[3] = (lane &  4) ? -ptot : ptot;
    z[4] = (lane &  2) ? -ptot : ptot;
    z[5] = (lane &  1) ? -ptot : ptot;
    z[6] = z6; z[7] = z7; z[8] = z8; z[9] = z9;

    #pragma unroll
    for (int q = 0; q < NQ; ++q) {
        #pragma unroll
        for (int m = 32; m > 0; m >>= 1)
            z[q] += __shfl_xor(z[q], m, 64);
    }
    if (lane == 0) {
        #pragma unroll
        for (int q = 0; q < NQ; ++q) out[b * NQ + q] = z[q];
    }
}

extern "C" void kernel_launch(void* const* d_in, const int* in_sizes, int n_in,
                              void* d_out, int out_size, void* d_ws, size_t ws_size,
                              hipStream_t stream) {
    const float* x = (const float*)d_in[0];        // (BATCH, NQ) fp32
    const float* w = (const float*)d_in[1];        // (NDEPTH, NQ) fp32
    float* out = (float*)d_out;                    // (BATCH, NQ) fp32
    const int B = in_sizes[0] / NQ;
    vql_kernel<<<(B + 3) / 4, 256, 0, stream>>>(x, w, out, B);
}

// Round 3
// 23.909 us; speedup vs baseline: 3.0966x; 1.3762x over previous
//
#include <hip/hip_runtime.h>
#include <math.h>

#define NQ 10
#define NDEPTH 4
#define NR 16              // amplitudes per lane (2^4)

// One WAVE per batch element: 64 lanes x 16 complex amps = 1024 amplitudes.
// Flat index i = lane*16 + r. Qubit q <-> bit k = 9-q of i:
//   q 0..5  -> lane bit (5-q), xor mask M = 32 >> q
//   q 6..9  -> register bit (9-q)
// Cross-lane xor via DPP (M=1,2,8: VALU, no DS latency), ds_swizzle (M=4,16),
// ds_bpermute with precomputed address (M=32 and the composed CNOT chain).

__device__ __forceinline__ float xf(int i) { return __int_as_float(i); }
__device__ __forceinline__ int   fx(float f) { return __float_as_int(f); }

template<int M>
__device__ __forceinline__ float lane_xor(float v, int addr32) {
    if constexpr (M == 1)        // quad_perm [1,0,3,2]
        return xf(__builtin_amdgcn_update_dpp(fx(v), fx(v), 0xB1, 0xF, 0xF, true));
    else if constexpr (M == 2)   // quad_perm [2,3,0,1]
        return xf(__builtin_amdgcn_update_dpp(fx(v), fx(v), 0x4E, 0xF, 0xF, true));
    else if constexpr (M == 8)   // row_ror:8 == xor 8 within 16-lane row
        return xf(__builtin_amdgcn_update_dpp(fx(v), fx(v), 0x128, 0xF, 0xF, true));
    else if constexpr (M == 4)   // ds_swizzle bit-mode xor 4
        return xf(__builtin_amdgcn_ds_swizzle(fx(v), 0x101F));
    else if constexpr (M == 16)  // ds_swizzle bit-mode xor 16
        return xf(__builtin_amdgcn_ds_swizzle(fx(v), 0x401F));
    else                         // M == 32: bpermute, addr32 = (lane^32)<<2
        return xf(__builtin_amdgcn_ds_bpermute(addr32, fx(v)));
}

template<int M, bool IS_RX>
__device__ __forceinline__ void rot_lanebit(float (&re)[NR], float (&im)[NR],
                                            float c, float s, int lane, int addr32) {
    const float sgn = (lane & M) ? s : -s;   // RY only
    #pragma unroll
    for (int r = 0; r < NR; ++r) {
        const float pre = lane_xor<M>(re[r], addr32);
        const float pim = lane_xor<M>(im[r], addr32);
        if (IS_RX) {
            re[r] = c * re[r] + s * pim;
            im[r] = c * im[r] - s * pre;
        } else {
            re[r] = c * re[r] + sgn * pre;
            im[r] = c * im[r] + sgn * pim;
        }
    }
}

template<int J, bool IS_RX>
__device__ __forceinline__ void rot_regbit(float (&re)[NR], float (&im)[NR],
                                           float c, float s) {
    #pragma unroll
    for (int r0 = 0; r0 < NR; ++r0) {
        if (r0 & (1 << J)) continue;
        const int r1 = r0 | (1 << J);
        const float R0 = re[r0], M0 = im[r0];
        const float R1 = re[r1], M1 = im[r1];
        if (IS_RX) {
            re[r0] = c * R0 + s * M1;
            im[r0] = c * M0 - s * R1;
            re[r1] = c * R1 + s * M0;
            im[r1] = c * M1 - s * R0;
        } else {
            re[r0] = c * R0 - s * R1;
            im[r0] = c * M0 - s * M1;
            re[r1] = s * R0 + c * R1;
            im[r1] = s * M0 + c * M1;
        }
    }
}

__global__ __launch_bounds__(256) void vql_kernel(
    const float* __restrict__ x,     // (B, NQ)
    const float* __restrict__ w,     // (NDEPTH, NQ)
    float* __restrict__ out,         // (B, NQ)
    int B)
{
    const int lane = threadIdx.x & 63;
    const int b = blockIdx.x * 4 + (threadIdx.x >> 6);
    if (b >= B) return;

    // precomputed cross-lane addresses (hoisted out of all gates)
    const int addr32 = ((lane ^ 32) << 2);
    int j = lane;                       // composed CNOT(0->1..4->5) source lane
    j ^= ((j >> 1) & 1);                // C(4->5)
    j ^= ((j >> 2) & 1) << 1;           // C(3->4)
    j ^= ((j >> 3) & 1) << 2;           // C(2->3)
    j ^= ((j >> 4) & 1) << 3;           // C(1->2)
    j ^= ((j >> 5) & 1) << 4;           // C(0->1)
    const int jaddr = j << 2;

    float re[NR], im[NR];
    #pragma unroll
    for (int r = 0; r < NR; ++r) { re[r] = 0.f; im[r] = 0.f; }
    if (lane == 0) re[0] = 1.f;

    // ---- RY encoding layer ----
    {
        float c, s;
        #define RY_LANE(q) { __sincosf(0.5f * x[b*NQ + (q)], &s, &c); \
                             rot_lanebit<(32 >> (q)), false>(re, im, c, s, lane, addr32); }
        RY_LANE(0) RY_LANE(1) RY_LANE(2) RY_LANE(3) RY_LANE(4) RY_LANE(5)
        #undef RY_LANE
        __sincosf(0.5f * x[b*NQ + 6], &s, &c); rot_regbit<3, false>(re, im, c, s);
        __sincosf(0.5f * x[b*NQ + 7], &s, &c); rot_regbit<2, false>(re, im, c, s);
        __sincosf(0.5f * x[b*NQ + 8], &s, &c); rot_regbit<1, false>(re, im, c, s);
        __sincosf(0.5f * x[b*NQ + 9], &s, &c); rot_regbit<0, false>(re, im, c, s);
    }

    // ---- variational layers ----
    #pragma unroll
    for (int l = 0; l < NDEPTH; ++l) {
        float c, s;
        #define RX_LANE(q) { __sincosf(0.5f * w[l*NQ + (q)], &s, &c); \
                             rot_lanebit<(32 >> (q)), true>(re, im, c, s, lane, addr32); }
        RX_LANE(0) RX_LANE(1) RX_LANE(2) RX_LANE(3) RX_LANE(4) RX_LANE(5)
        #undef RX_LANE
        __sincosf(0.5f * w[l*NQ + 6], &s, &c); rot_regbit<3, true>(re, im, c, s);
        __sincosf(0.5f * w[l*NQ + 7], &s, &c); rot_regbit<2, true>(re, im, c, s);
        __sincosf(0.5f * w[l*NQ + 8], &s, &c); rot_regbit<1, true>(re, im, c, s);
        __sincosf(0.5f * w[l*NQ + 9], &s, &c); rot_regbit<0, true>(re, im, c, s);

        // CNOTs (0->1)...(4->5): composed lane permutation, one bpermute pass
        #pragma unroll
        for (int r = 0; r < NR; ++r) {
            re[r] = xf(__builtin_amdgcn_ds_bpermute(jaddr, fx(re[r])));
            im[r] = xf(__builtin_amdgcn_ds_bpermute(jaddr, fx(im[r])));
        }
        // C(5->6): ctrl lane bit0, tgt reg bit3 -> conditional reg swap
        {
            const bool ctl = (lane & 1) != 0;
            #pragma unroll
            for (int r = 0; r < 8; ++r) {
                const float a0 = re[r], a1 = re[r + 8];
                re[r] = ctl ? a1 : a0;  re[r + 8] = ctl ? a0 : a1;
                const float b0 = im[r], b1 = im[r + 8];
                im[r] = ctl ? b1 : b0;  im[r + 8] = ctl ? b0 : b1;
            }
        }
        // C(6->7): regs bit3=1 swap bit2
        #pragma unroll
        for (int r = 8; r < 12; ++r) {
            float t = re[r]; re[r] = re[r + 4]; re[r + 4] = t;
            t = im[r]; im[r] = im[r + 4]; im[r + 4] = t;
        }
        // C(7->8): regs bit2=1 swap bit1
        {
            const int rs[4] = {4, 5, 12, 13};
            #pragma unroll
            for (int k = 0; k < 4; ++k) {
                const int r = rs[k];
                float t = re[r]; re[r] = re[r + 2]; re[r + 2] = t;
                t = im[r]; im[r] = im[r + 2]; im[r + 2] = t;
            }
        }
        // C(8->9): regs bit1=1 swap bit0
        {
            const int rs[4] = {2, 6, 10, 14};
            #pragma unroll
            for (int k = 0; k < 4; ++k) {
                const int r = rs[k];
                float t = re[r]; re[r] = re[r + 1]; re[r + 1] = t;
                t = im[r]; im[r] = im[r + 1]; im[r + 1] = t;
            }
        }
        // C(9->0): ctrl reg bit0, tgt lane mask 32 -> bpermute odd regs
        #pragma unroll
        for (int r = 1; r < NR; r += 2) {
            re[r] = lane_xor<32>(re[r], addr32);
            im[r] = lane_xor<32>(im[r], addr32);
        }
    }

    // ---- readout ----
    float p[NR];
    #pragma unroll
    for (int r = 0; r < NR; ++r) p[r] = re[r] * re[r] + im[r] * im[r];

    float ptot = 0.f, z6 = 0.f, z7 = 0.f, z8 = 0.f, z9 = 0.f;
    #pragma unroll
    for (int r = 0; r < NR; ++r) {
        ptot += p[r];
        z6 += (r & 8) ? -p[r] : p[r];
        z7 += (r & 4) ? -p[r] : p[r];
        z8 += (r & 2) ? -p[r] : p[r];
        z9 += (r & 1) ? -p[r] : p[r];
    }
    float z[NQ];
    z[0] = (lane & 32) ? -ptot : ptot;
    z[1] = (lane & 16) ? -ptot : ptot;
    z[2] = (lane &  8) ? -ptot : ptot;
    z[3] = (lane &  4) ? -ptot : ptot;
    z[4] = (lane &  2) ? -ptot : ptot;
    z[5] = (lane &  1) ? -ptot : ptot;
    z[6] = z6; z[7] = z7; z[8] = z8; z[9] = z9;

    #pragma unroll
    for (int q = 0; q < NQ; ++q) {
        z[q] += lane_xor<1>(z[q], addr32);
        z[q] += lane_xor<2>(z[q], addr32);
        z[q] += lane_xor<4>(z[q], addr32);
        z[q] += lane_xor<8>(z[q], addr32);
        z[q] += lane_xor<16>(z[q], addr32);
        z[q] += lane_xor<32>(z[q], addr32);
    }
    if (lane == 0) {
        #pragma unroll
        for (int q = 0; q < NQ; ++q) out[b * NQ + q] = z[q];
    }
}

extern "C" void kernel_launch(void* const* d_in, const int* in_sizes, int n_in,
                              void* d_out, int out_size, void* d_ws, size_t ws_size,
                              hipStream_t stream) {
    const float* x = (const float*)d_in[0];        // (BATCH, NQ) fp32
    const float* w = (const float*)d_in[1];        // (NDEPTH, NQ) fp32
    float* out = (float*)d_out;                    // (BATCH, NQ) fp32
    const int B = in_sizes[0] / NQ;
    vql_kernel<<<(B + 3) / 4, 256, 0, stream>>>(x, w, out, B);
}

// Round 4
// 20.036 us; speedup vs baseline: 3.6953x; 1.1933x over previous
//
#include <hip/hip_runtime.h>
#include <math.h>

#define NQ 10
#define NDEPTH 4
#define NR 16              // amplitudes per lane (2^4)

// One WAVE per batch element: 64 lanes x 16 complex amps = 1024 amplitudes.
// Flat index i = lane*16 + r. Qubit q <-> bit k = 9-q of i:
//   q 0..5  -> lane bit (5-q), xor mask M = 32 >> q
//   q 6..9  -> register bit (9-q)
// Encoding RY layer + layer-0 RX act on a product state -> folded into a
// direct analytic product-state construction (no gates, no shuffles).
// Cross-lane xor via DPP (M=1,2,8), ds_swizzle (M=4,16), ds_bpermute (M=32,
// composed CNOT chain) with hoisted addresses.

__device__ __forceinline__ float xf(int i) { return __int_as_float(i); }
__device__ __forceinline__ int   fx(float f) { return __float_as_int(f); }

template<int M>
__device__ __forceinline__ float lane_xor(float v, int addr32) {
    if constexpr (M == 1)        // quad_perm [1,0,3,2]
        return xf(__builtin_amdgcn_update_dpp(fx(v), fx(v), 0xB1, 0xF, 0xF, true));
    else if constexpr (M == 2)   // quad_perm [2,3,0,1]
        return xf(__builtin_amdgcn_update_dpp(fx(v), fx(v), 0x4E, 0xF, 0xF, true));
    else if constexpr (M == 8)   // row_ror:8 == xor 8 within 16-lane row
        return xf(__builtin_amdgcn_update_dpp(fx(v), fx(v), 0x128, 0xF, 0xF, true));
    else if constexpr (M == 4)   // ds_swizzle bit-mode xor 4
        return xf(__builtin_amdgcn_ds_swizzle(fx(v), 0x101F));
    else if constexpr (M == 16)  // ds_swizzle bit-mode xor 16
        return xf(__builtin_amdgcn_ds_swizzle(fx(v), 0x401F));
    else                         // M == 32: bpermute, addr32 = (lane^32)<<2
        return xf(__builtin_amdgcn_ds_bpermute(addr32, fx(v)));
}

template<int M>
__device__ __forceinline__ void rx_lanebit(float (&re)[NR], float (&im)[NR],
                                           float c, float s, int addr32) {
    #pragma unroll
    for (int r = 0; r < NR; ++r) {
        const float pre = lane_xor<M>(re[r], addr32);
        const float pim = lane_xor<M>(im[r], addr32);
        re[r] = c * re[r] + s * pim;
        im[r] = c * im[r] - s * pre;
    }
}

template<int J>
__device__ __forceinline__ void rx_regbit(float (&re)[NR], float (&im)[NR],
                                          float c, float s) {
    #pragma unroll
    for (int r0 = 0; r0 < NR; ++r0) {
        if (r0 & (1 << J)) continue;
        const int r1 = r0 | (1 << J);
        const float R0 = re[r0], M0 = im[r0];
        const float R1 = re[r1], M1 = im[r1];
        re[r0] = c * R0 + s * M1;
        im[r0] = c * M0 - s * R1;
        re[r1] = c * R1 + s * M0;
        im[r1] = c * M1 - s * R0;
    }
}

__device__ __forceinline__ void cnot_ring(float (&re)[NR], float (&im)[NR],
                                          int lane, int jaddr, int addr32) {
    // CNOTs (0->1)...(4->5): composed lane permutation, one bpermute pass
    #pragma unroll
    for (int r = 0; r < NR; ++r) {
        re[r] = xf(__builtin_amdgcn_ds_bpermute(jaddr, fx(re[r])));
        im[r] = xf(__builtin_amdgcn_ds_bpermute(jaddr, fx(im[r])));
    }
    // C(5->6): ctrl lane bit0, tgt reg bit3 -> conditional reg swap
    {
        const bool ctl = (lane & 1) != 0;
        #pragma unroll
        for (int r = 0; r < 8; ++r) {
            const float a0 = re[r], a1 = re[r + 8];
            re[r] = ctl ? a1 : a0;  re[r + 8] = ctl ? a0 : a1;
            const float b0 = im[r], b1 = im[r + 8];
            im[r] = ctl ? b1 : b0;  im[r + 8] = ctl ? b0 : b1;
        }
    }
    // C(6->7): regs bit3=1 swap bit2
    #pragma unroll
    for (int r = 8; r < 12; ++r) {
        float t = re[r]; re[r] = re[r + 4]; re[r + 4] = t;
        t = im[r]; im[r] = im[r + 4]; im[r + 4] = t;
    }
    // C(7->8): regs bit2=1 swap bit1
    {
        const int rs[4] = {4, 5, 12, 13};
        #pragma unroll
        for (int k = 0; k < 4; ++k) {
            const int r = rs[k];
            float t = re[r]; re[r] = re[r + 2]; re[r + 2] = t;
            t = im[r]; im[r] = im[r + 2]; im[r + 2] = t;
        }
    }
    // C(8->9): regs bit1=1 swap bit0
    {
        const int rs[4] = {2, 6, 10, 14};
        #pragma unroll
        for (int k = 0; k < 4; ++k) {
            const int r = rs[k];
            float t = re[r]; re[r] = re[r + 1]; re[r + 1] = t;
            t = im[r]; im[r] = im[r + 1]; im[r + 1] = t;
        }
    }
    // C(9->0): ctrl reg bit0, tgt lane mask 32 -> bpermute odd regs
    #pragma unroll
    for (int r = 1; r < NR; r += 2) {
        re[r] = lane_xor<32>(re[r], addr32);
        im[r] = lane_xor<32>(im[r], addr32);
    }
}

__global__ __launch_bounds__(256, 2) void vql_kernel(
    const float* __restrict__ x,     // (B, NQ)
    const float* __restrict__ w,     // (NDEPTH, NQ)
    float* __restrict__ out,         // (B, NQ)
    int B)
{
    const int lane = threadIdx.x & 63;
    const int b = blockIdx.x * 4 + (threadIdx.x >> 6);
    if (b >= B) return;

    // hoisted cross-lane addresses
    const int addr32 = ((lane ^ 32) << 2);
    int j = lane;                       // composed CNOT(0->1..4->5) source lane
    j ^= ((j >> 1) & 1);
    j ^= ((j >> 2) & 1) << 1;
    j ^= ((j >> 3) & 1) << 2;
    j ^= ((j >> 4) & 1) << 3;
    j ^= ((j >> 5) & 1) << 4;
    const int jaddr = j << 2;

    // ---- preload all per-batch angles up-front (one memory latency) ----
    float xa[NQ];
    #pragma unroll
    for (int q = 0; q < NQ; ++q) xa[q] = 0.5f * x[b * NQ + q];
    // w is grid-uniform -> s_load; index with constant offsets only.

    // ---- analytic product state: amp = prod_q (RX(w0q) RY(xq) |0>) ----
    // RY(th)|0> = (cy, sy);  RX(ph)(cy,sy) = (c*cy - i s*sy, -i s*cy + c*sy)
    float v0r[NQ], v0i[NQ], v1r[NQ], v1i[NQ];
    #pragma unroll
    for (int q = 0; q < NQ; ++q) {
        float sy, cy, s, c;
        __sincosf(xa[q], &sy, &cy);
        __sincosf(0.5f * w[q], &s, &c);   // layer-0 weights
        v0r[q] = c * cy;  v0i[q] = -s * sy;
        v1r[q] = c * sy;  v1i[q] = -s * cy;
    }
    // lane factor: qubits 0..5, qubit q <-> lane bit (5-q)
    float Pr = 1.f, Pi = 0.f;
    #pragma unroll
    for (int q = 0; q < 6; ++q) {
        const int bit = (lane >> (5 - q)) & 1;
        const float ar = bit ? v1r[q] : v0r[q];
        const float ai = bit ? v1i[q] : v0i[q];
        const float nr = Pr * ar - Pi * ai;
        const float ni = Pr * ai + Pi * ar;
        Pr = nr; Pi = ni;
    }
    // reg factors: r bit3 = qubit6, bit2 = qubit7, bit1 = qubit8, bit0 = qubit9
    float hr[4], hi4[4], gr[4], gi4[4];
    #pragma unroll
    for (int t2 = 0; t2 < 4; ++t2) {
        const int bA = (t2 >> 1) & 1, bB = t2 & 1;
        {   // qubits 6,7
            const float ar = bA ? v1r[6] : v0r[6], ai = bA ? v1i[6] : v0i[6];
            const float br = bB ? v1r[7] : v0r[7], bi = bB ? v1i[7] : v0i[7];
            hr[t2] = ar * br - ai * bi;
            hi4[t2] = ar * bi + ai * br;
        }
        {   // qubits 8,9
            const float ar = bA ? v1r[8] : v0r[8], ai = bA ? v1i[8] : v0i[8];
            const float br = bB ? v1r[9] : v0r[9], bi = bB ? v1i[9] : v0i[9];
            gr[t2] = ar * br - ai * bi;
            gi4[t2] = ar * bi + ai * br;
        }
    }
    float re[NR], im[NR];
    #pragma unroll
    for (int r = 0; r < NR; ++r) {
        const float ar = hr[(r >> 2) & 3], ai = hi4[(r >> 2) & 3];
        const float br = gr[r & 3],        bi = gi4[r & 3];
        const float qr = ar * br - ai * bi;
        const float qi = ar * bi + ai * br;
        re[r] = Pr * qr - Pi * qi;
        im[r] = Pr * qi + Pi * qr;
    }

    // ---- layer 0 CNOT ring (RX layer 0 was folded into the init) ----
    cnot_ring(re, im, lane, jaddr, addr32);

    // ---- layers 1..3: RX all qubits + CNOT ring ----
    #pragma unroll
    for (int l = 1; l < NDEPTH; ++l) {
        float c[NQ], s[NQ];
        #pragma unroll
        for (int q = 0; q < NQ; ++q)
            __sincosf(0.5f * w[l * NQ + q], &s[q], &c[q]);
        rx_lanebit<32>(re, im, c[0], s[0], addr32);
        rx_lanebit<16>(re, im, c[1], s[1], addr32);
        rx_lanebit< 8>(re, im, c[2], s[2], addr32);
        rx_lanebit< 4>(re, im, c[3], s[3], addr32);
        rx_lanebit< 2>(re, im, c[4], s[4], addr32);
        rx_lanebit< 1>(re, im, c[5], s[5], addr32);
        rx_regbit<3>(re, im, c[6], s[6]);
        rx_regbit<2>(re, im, c[7], s[7]);
        rx_regbit<1>(re, im, c[8], s[8]);
        rx_regbit<0>(re, im, c[9], s[9]);
        cnot_ring(re, im, lane, jaddr, addr32);
    }

    // ---- readout ----
    float p[NR];
    #pragma unroll
    for (int r = 0; r < NR; ++r) p[r] = re[r] * re[r] + im[r] * im[r];

    float ptot = 0.f, z6 = 0.f, z7 = 0.f, z8 = 0.f, z9 = 0.f;
    #pragma unroll
    for (int r = 0; r < NR; ++r) {
        ptot += p[r];
        z6 += (r & 8) ? -p[r] : p[r];
        z7 += (r & 4) ? -p[r] : p[r];
        z8 += (r & 2) ? -p[r] : p[r];
        z9 += (r & 1) ? -p[r] : p[r];
    }
    float z[NQ];
    z[0] = (lane & 32) ? -ptot : ptot;
    z[1] = (lane & 16) ? -ptot : ptot;
    z[2] = (lane &  8) ? -ptot : ptot;
    z[3] = (lane &  4) ? -ptot : ptot;
    z[4] = (lane &  2) ? -ptot : ptot;
    z[5] = (lane &  1) ? -ptot : ptot;
    z[6] = z6; z[7] = z7; z[8] = z8; z[9] = z9;

    #pragma unroll
    for (int q = 0; q < NQ; ++q) {
        z[q] += lane_xor<1>(z[q], addr32);
        z[q] += lane_xor<2>(z[q], addr32);
        z[q] += lane_xor<4>(z[q], addr32);
        z[q] += lane_xor<8>(z[q], addr32);
        z[q] += lane_xor<16>(z[q], addr32);
        z[q] += lane_xor<32>(z[q], addr32);
    }
    if (lane == 0) {
        #pragma unroll
        for (int q = 0; q < NQ; ++q) out[b * NQ + q] = z[q];
    }
}

extern "C" void kernel_launch(void* const* d_in, const int* in_sizes, int n_in,
                              void* d_out, int out_size, void* d_ws, size_t ws_size,
                              hipStream_t stream) {
    const float* x = (const float*)d_in[0];        // (BATCH, NQ) fp32
    const float* w = (const float*)d_in[1];        // (NDEPTH, NQ) fp32
    float* out = (float*)d_out;                    // (BATCH, NQ) fp32
    const int B = in_sizes[0] / NQ;
    vql_kernel<<<(B + 3) / 4, 256, 0, stream>>>(x, w, out, B);
}